// Round 1
// baseline (475.032 us; speedup 1.0000x reference)
//
#include <hip/hip_runtime.h>

#define BATCH 4
#define SEQ   2048
#define DIM   1024
#define HD    64
#define NROW  (BATCH * SEQ)

// ---------------------------------------------------------------------------
// Stage 1: QKV projection.  grid = (NROW/64, 3), block = 256 (4 waves).
// Each block computes a 64-row x 64-col tile of one of {q,k,v}.
// x tile staged in LDS (row stride 68 floats keeps float4 16B alignment and
// breaks power-of-2 bank strides); per-wave rows are uniform -> LDS reads are
// broadcast (free).  W reads are lane-consecutive (coalesced, L2-resident).
// ---------------------------------------------------------------------------
__global__ __launch_bounds__(256) void qkv_proj_kernel(
    const float* __restrict__ x,
    const float* __restrict__ Wq, const float* __restrict__ bq,
    const float* __restrict__ Wk, const float* __restrict__ bk,
    const float* __restrict__ Wv, const float* __restrict__ bv,
    float* __restrict__ qkv)
{
    __shared__ float xs[64][68];

    const int which = blockIdx.y;
    const float* __restrict__ W    = (which == 0) ? Wq : (which == 1) ? Wk : Wv;
    const float* __restrict__ bias = (which == 0) ? bq : (which == 1) ? bk : bv;
    float* __restrict__ out = qkv + (size_t)which * NROW * HD;

    const int tid = threadIdx.x;
    const int col = tid & 63;   // output column, lane-consecutive
    const int rg  = tid >> 6;   // wave id: row group 0..3
    const int rowbase = blockIdx.x * 64;

    float acc[16];
#pragma unroll
    for (int r = 0; r < 16; ++r) acc[r] = 0.f;

    for (int kc = 0; kc < DIM; kc += 64) {
        __syncthreads();
        // cooperative load of the 64x64 x tile (coalesced float4)
#pragma unroll
        for (int i = 0; i < 4; ++i) {
            int f4 = tid + i * 256;         // 0..1023 float4 slots
            int r  = f4 >> 4;               // 16 float4 per row
            int c  = (f4 & 15) * 4;
            float4 v = *reinterpret_cast<const float4*>(
                &x[(size_t)(rowbase + r) * DIM + kc + c]);
            *reinterpret_cast<float4*>(&xs[r][c]) = v;
        }
        __syncthreads();

#pragma unroll 4
        for (int k4 = 0; k4 < 16; ++k4) {
            const float w0 = W[(size_t)(kc + k4 * 4 + 0) * HD + col];
            const float w1 = W[(size_t)(kc + k4 * 4 + 1) * HD + col];
            const float w2 = W[(size_t)(kc + k4 * 4 + 2) * HD + col];
            const float w3 = W[(size_t)(kc + k4 * 4 + 3) * HD + col];
#pragma unroll
            for (int r = 0; r < 16; ++r) {
                // broadcast LDS read (all lanes in the wave share the row)
                float4 xv = *reinterpret_cast<const float4*>(&xs[rg * 16 + r][k4 * 4]);
                acc[r] = fmaf(xv.x, w0, acc[r]);
                acc[r] = fmaf(xv.y, w1, acc[r]);
                acc[r] = fmaf(xv.z, w2, acc[r]);
                acc[r] = fmaf(xv.w, w3, acc[r]);
            }
        }
    }

    const float bb = bias[col];
#pragma unroll
    for (int r = 0; r < 16; ++r) {
        out[(size_t)(rowbase + rg * 16 + r) * HD + col] = acc[r] + bb;
    }
}

// ---------------------------------------------------------------------------
// Stage 2: causal flash attention.  grid = NROW/4 blocks, block = 256.
// Each wave owns one query row (q held fully in registers, lane d holds o[d]).
// K tile staged TRANSPOSED (KsT[d][key]) so score reads are lane-consecutive;
// V tile natural orientation so PV reads are lane-consecutive.  Stride 68
// keeps alignment; lane-consecutive @ stride 68 => 2-way bank alias (free).
// Online softmax across the 64 per-lane scores via __shfl_xor butterflies.
// ---------------------------------------------------------------------------
__global__ __launch_bounds__(256) void attn_kernel(
    const float* __restrict__ qkv, float* __restrict__ out)
{
    __shared__ float KsT[64][68];  // [d][key]
    __shared__ float Vs[64][68];   // [key][d]

    const float* __restrict__ Q = qkv;
    const float* __restrict__ K = qkv + (size_t)NROW * HD;
    const float* __restrict__ V = qkv + (size_t)2 * NROW * HD;

    const int tid  = threadIdx.x;
    const int lane = tid & 63;
    const int w    = tid >> 6;            // wave 0..3
    const int rowbase = blockIdx.x * 4;   // 4 consecutive rows, same batch
    const int qbase   = rowbase & (SEQ - 1);
    const int b       = rowbase / SEQ;
    const int qi      = qbase + w;        // this wave's query position
    const size_t boff = (size_t)b * SEQ * HD;

    // q row fully in registers (same addresses across lanes -> broadcast)
    float qf[64];
#pragma unroll
    for (int i = 0; i < 16; ++i) {
        float4 v = *reinterpret_cast<const float4*>(&Q[boff + (size_t)qi * HD + i * 4]);
        qf[i * 4 + 0] = v.x; qf[i * 4 + 1] = v.y;
        qf[i * 4 + 2] = v.z; qf[i * 4 + 3] = v.w;
    }

    const float NEG_INF = -__builtin_inff();
    float m = NEG_INF, l = 0.f, o = 0.f;     // o: lane d accumulates out[d]
    const int ntiles   = (qi >> 6) + 1;
    const int maxtiles = ((qbase + 3) >> 6) + 1;

    for (int t = 0; t < maxtiles; ++t) {
        __syncthreads();
        // cooperative load: K tile (transposed into LDS), V tile (natural)
#pragma unroll
        for (int i = 0; i < 4; ++i) {
            int f4 = tid + i * 256;
            int r  = f4 >> 4;
            int c  = (f4 & 15) * 4;
            const float4 kv = *reinterpret_cast<const float4*>(
                &K[boff + (size_t)(t * 64 + r) * HD + c]);
            KsT[c + 0][r] = kv.x;
            KsT[c + 1][r] = kv.y;
            KsT[c + 2][r] = kv.z;
            KsT[c + 3][r] = kv.w;
            const float4 vv = *reinterpret_cast<const float4*>(
                &V[boff + (size_t)(t * 64 + r) * HD + c]);
            *reinterpret_cast<float4*>(&Vs[r][c]) = vv;
        }
        __syncthreads();
        if (t >= ntiles) continue;  // wave done; still participates in barriers

        // scores: lane L computes s for key (t*64 + L)
        float s = 0.f;
#pragma unroll
        for (int d = 0; d < 64; ++d) {
            s = fmaf(qf[d], KsT[d][lane], s);
        }
        s *= 0.125f;  // 1/sqrt(64); -inf mask applied after => same as ref
        const int kmax = qi - t * 64;
        if (lane > kmax) s = NEG_INF;

        // online softmax over this tile's 64 scores
        float smax = s;
#pragma unroll
        for (int off = 32; off >= 1; off >>= 1)
            smax = fmaxf(smax, __shfl_xor(smax, off));
        const float mnew = fmaxf(m, smax);
        const float p    = __expf(s - mnew);
        float psum = p;
#pragma unroll
        for (int off = 32; off >= 1; off >>= 1)
            psum += __shfl_xor(psum, off);
        const float corr = (m == NEG_INF) ? 0.f : __expf(m - mnew);
        l = l * corr + psum;
        o = o * corr;

        // PV: o[lane] += sum_L p[L] * V[L][lane]
#pragma unroll
        for (int L = 0; L < 64; ++L) {
            o = fmaf(__shfl(p, L), Vs[L][lane], o);
        }
        m = mnew;
    }

    out[boff + (size_t)qi * HD + lane] = o / l;
}

// ---------------------------------------------------------------------------
extern "C" void kernel_launch(void* const* d_in, const int* in_sizes, int n_in,
                              void* d_out, int out_size, void* d_ws, size_t ws_size,
                              hipStream_t stream)
{
    (void)in_sizes; (void)n_in; (void)out_size; (void)ws_size;
    const float* x  = (const float*)d_in[0];
    const float* Wq = (const float*)d_in[1];
    const float* bq = (const float*)d_in[2];
    const float* Wk = (const float*)d_in[3];
    const float* bk = (const float*)d_in[4];
    const float* Wv = (const float*)d_in[5];
    const float* bv = (const float*)d_in[6];
    float* out = (float*)d_out;
    float* qkv = (float*)d_ws;  // [3][NROW][HD] fp32 = 6 MiB

    dim3 gProj(NROW / 64, 3);
    qkv_proj_kernel<<<gProj, 256, 0, stream>>>(x, Wq, bq, Wk, bk, Wv, bv, qkv);

    attn_kernel<<<NROW / 4, 256, 0, stream>>>(qkv, out);
}

// Round 2
// 119.314 us; speedup vs baseline: 3.9814x; 3.9814x over previous
//
#include <hip/hip_runtime.h>

#define SEQ  2048
#define DIM  1024
#define HD   64
#define NROW 8192

typedef float f32x4  __attribute__((ext_vector_type(4)));
typedef short bf16x8 __attribute__((ext_vector_type(8)));

__device__ __forceinline__ short f2bf(float x) {
    union { float f; unsigned u; } v; v.f = x;
    unsigned r = v.u + 0x7FFFu + ((v.u >> 16) & 1u);
    return (short)(r >> 16);
}

#define MFMA16(a, b, c) __builtin_amdgcn_mfma_f32_16x16x32_bf16((a), (b), (c), 0, 0, 0)

// ---------------------------------------------------------------------------
// wprep: repack Wq/Wk/Wv (fp32 [1024][64]) into bf16 MFMA B-fragment order:
// wfrag[which][kstep 32][nfrag 4][lane 64][8].  Lane l, elem j holds
// W[kstep*32 + (l>>4)*8 + j][nfrag*16 + (l&15)].  Writes coalesced 16B/lane.
// ---------------------------------------------------------------------------
__global__ __launch_bounds__(256) void wprep_kernel(
    const float* __restrict__ Wq, const float* __restrict__ Wk,
    const float* __restrict__ Wv, short* __restrict__ wfrag)
{
    const int idx = blockIdx.x * 256 + threadIdx.x;   // 0..24575
    const int l  = idx & 63;
    const int n  = (idx >> 6) & 3;
    const int ks = (idx >> 8) & 31;
    const int w  = idx >> 13;
    const float* __restrict__ W = (w == 0) ? Wq : (w == 1) ? Wk : Wv;
    bf16x8 v;
#pragma unroll
    for (int j = 0; j < 8; ++j)
        v[j] = f2bf(W[(size_t)(ks * 32 + (l >> 4) * 8 + j) * HD + n * 16 + (l & 15)]);
    *reinterpret_cast<bf16x8*>(wfrag + (size_t)idx * 8) = v;
}

// ---------------------------------------------------------------------------
// proj: qkv = x*W + b via MFMA.  1 wave/block, 16 rows/wave, grid 512.
// A-frag from x fp32 (2x float4, cvt to bf16), B-frags from wfrag (16B loads).
// Q stored pre-scaled by 0.125 (exact exponent shift in bf16).
// ---------------------------------------------------------------------------
__global__ __launch_bounds__(64) void proj_kernel(
    const float* __restrict__ x, const short* __restrict__ wfrag,
    const float* __restrict__ bq, const float* __restrict__ bk,
    const float* __restrict__ bv,
    short* __restrict__ Qs, short* __restrict__ Kb, short* __restrict__ Vb)
{
    const int lane = threadIdx.x;
    const int c = lane & 15;
    const int g = lane >> 4;
    const int r0 = blockIdx.x * 16;

    f32x4 acc[3][4] = {};

    for (int ks = 0; ks < 32; ++ks) {
        const float* xp = x + (size_t)(r0 + c) * DIM + ks * 32 + g * 8;
        float4 a0 = *reinterpret_cast<const float4*>(xp);
        float4 a1 = *reinterpret_cast<const float4*>(xp + 4);
        float av[8] = {a0.x, a0.y, a0.z, a0.w, a1.x, a1.y, a1.z, a1.w};
        bf16x8 af;
#pragma unroll
        for (int j = 0; j < 8; ++j) af[j] = f2bf(av[j]);
#pragma unroll
        for (int w = 0; w < 3; ++w) {
#pragma unroll
            for (int n = 0; n < 4; ++n) {
                bf16x8 bfr = *reinterpret_cast<const bf16x8*>(
                    wfrag + ((size_t)((w * 32 + ks) * 4 + n) * 64 + lane) * 8);
                acc[w][n] = MFMA16(af, bfr, acc[w][n]);
            }
        }
    }

    float bias[3][4];
#pragma unroll
    for (int n = 0; n < 4; ++n) {
        bias[0][n] = bq[n * 16 + c];
        bias[1][n] = bk[n * 16 + c];
        bias[2][n] = bv[n * 16 + c];
    }

#pragma unroll
    for (int n = 0; n < 4; ++n) {
#pragma unroll
        for (int i = 0; i < 4; ++i) {
            const size_t row = r0 + g * 4 + i;
            const size_t o = row * HD + n * 16 + c;
            Qs[o] = f2bf((acc[0][n][i] + bias[0][n]) * 0.125f);
            Kb[o] = f2bf(acc[1][n][i] + bias[1][n]);
            Vb[o] = f2bf(acc[2][n][i] + bias[2][n]);
        }
    }
}

// ---------------------------------------------------------------------------
// vtrans: Vb [8192][64] bf16 -> Vt [4][64][2048] bf16 via LDS transpose.
// ---------------------------------------------------------------------------
__global__ __launch_bounds__(256) void vtrans_kernel(
    const short* __restrict__ Vb, short* __restrict__ Vt)
{
    __shared__ short ts[64][72];
    const int tid = threadIdx.x;
    const int s0g = blockIdx.x * 64;
    const int b   = s0g >> 11;
    const int sb  = s0g & (SEQ - 1);

    {
        const int r = tid >> 2, ch = tid & 3;
        bf16x8 v0 = *reinterpret_cast<const bf16x8*>(Vb + (size_t)(s0g + r) * HD + ch * 16);
        bf16x8 v1 = *reinterpret_cast<const bf16x8*>(Vb + (size_t)(s0g + r) * HD + ch * 16 + 8);
        *reinterpret_cast<bf16x8*>(&ts[r][ch * 16]) = v0;
        *reinterpret_cast<bf16x8*>(&ts[r][ch * 16 + 8]) = v1;
    }
    __syncthreads();
    {
        const int d = tid >> 2, ch = tid & 3;
        bf16x8 o0, o1;
#pragma unroll
        for (int e = 0; e < 8; ++e) o0[e] = ts[ch * 16 + e][d];
#pragma unroll
        for (int e = 0; e < 8; ++e) o1[e] = ts[ch * 16 + 8 + e][d];
        short* dst = Vt + (((size_t)(b * 64 + d)) << 11) + sb + ch * 16;
        *reinterpret_cast<bf16x8*>(dst) = o0;
        *reinterpret_cast<bf16x8*>(dst + 8) = o1;
    }
}

// ---------------------------------------------------------------------------
// attn: flash attention, MFMA 16x16x32 bf16.  1 wave/block, 16 q-rows/wave,
// key-tiles of 64.  Q frags register-resident; K/V frags direct global 16B
// loads (L2-resident).  Online softmax over 16-lane groups.  P relayout via
// per-wave LDS scratch (no barriers needed).
// ---------------------------------------------------------------------------
__global__ __launch_bounds__(64) void attn_mfma_kernel(
    const short* __restrict__ Qs, const short* __restrict__ Kb,
    const short* __restrict__ Vt, float* __restrict__ out)
{
    __shared__ short P_lds[16][72];

    const int lane = threadIdx.x;
    const int c = lane & 15;
    const int g = lane >> 4;

    const int q0g   = blockIdx.x * 16;
    const int b     = q0g >> 11;
    const int qbase = q0g & (SEQ - 1);

    // Q A-fragments (pre-scaled by 0.125): rows q0g..q0g+15
    bf16x8 qf[2];
    qf[0] = *reinterpret_cast<const bf16x8*>(Qs + (size_t)(q0g + c) * HD + g * 8);
    qf[1] = *reinterpret_cast<const bf16x8*>(Qs + (size_t)(q0g + c) * HD + 32 + g * 8);

    f32x4 O[4] = {};
    float m_i[4], l_i[4];
#pragma unroll
    for (int i = 0; i < 4; ++i) { m_i[i] = -__builtin_inff(); l_i[i] = 0.f; }

    const int tlast = qbase >> 6;
    const size_t krow0 = (size_t)b * SEQ;

    for (int t = 0; t <= tlast; ++t) {
        const int key0 = t * 64;

        // ---- QK^T ----
        bf16x8 kf[4][2];
#pragma unroll
        for (int n = 0; n < 4; ++n) {
#pragma unroll
            for (int st = 0; st < 2; ++st) {
                kf[n][st] = *reinterpret_cast<const bf16x8*>(
                    Kb + (krow0 + key0 + n * 16 + c) * HD + st * 32 + g * 8);
            }
        }
        f32x4 S[4] = {};
#pragma unroll
        for (int st = 0; st < 2; ++st)
#pragma unroll
            for (int n = 0; n < 4; ++n)
                S[n] = MFMA16(qf[st], kf[n][st], S[n]);

        // causal mask (only the diagonal tile needs it)
        if (t == tlast) {
#pragma unroll
            for (int n = 0; n < 4; ++n)
#pragma unroll
                for (int i = 0; i < 4; ++i)
                    if (key0 + n * 16 + c > qbase + g * 4 + i)
                        S[n][i] = -__builtin_inff();
        }

        // ---- online softmax (rows live in 16-lane groups) ----
        float mx[4], corr[4], rs[4];
#pragma unroll
        for (int i = 0; i < 4; ++i)
            mx[i] = fmaxf(fmaxf(S[0][i], S[1][i]), fmaxf(S[2][i], S[3][i]));
#pragma unroll
        for (int off = 1; off <= 8; off <<= 1)
#pragma unroll
            for (int i = 0; i < 4; ++i)
                mx[i] = fmaxf(mx[i], __shfl_xor(mx[i], off, 64));
#pragma unroll
        for (int i = 0; i < 4; ++i) {
            const float mn = fmaxf(m_i[i], mx[i]);
            corr[i] = __expf(m_i[i] - mn);   // exp(-inf)=0 on first tile
            m_i[i] = mn;
            rs[i] = 0.f;
        }
#pragma unroll
        for (int n = 0; n < 4; ++n)
#pragma unroll
            for (int i = 0; i < 4; ++i) {
                const float p = __expf(S[n][i] - m_i[i]);  // -inf -> 0
                S[n][i] = p;
                rs[i] += p;
            }
#pragma unroll
        for (int off = 1; off <= 8; off <<= 1)
#pragma unroll
            for (int i = 0; i < 4; ++i)
                rs[i] += __shfl_xor(rs[i], off, 64);
#pragma unroll
        for (int i = 0; i < 4; ++i) l_i[i] = l_i[i] * corr[i] + rs[i];
#pragma unroll
        for (int n = 0; n < 4; ++n)
#pragma unroll
            for (int i = 0; i < 4; ++i) O[n][i] *= corr[i];

        // ---- P -> LDS (bf16) in A-fragment-readable layout ----
#pragma unroll
        for (int n = 0; n < 4; ++n)
#pragma unroll
            for (int i = 0; i < 4; ++i)
                P_lds[g * 4 + i][n * 16 + c] = f2bf(S[n][i]);
        // same-wave RAW: compiler inserts lgkmcnt, no barrier needed

        // ---- PV ----
#pragma unroll
        for (int st = 0; st < 2; ++st) {
            bf16x8 pf = *reinterpret_cast<const bf16x8*>(&P_lds[c][st * 32 + g * 8]);
#pragma unroll
            for (int n = 0; n < 4; ++n) {
                bf16x8 vf = *reinterpret_cast<const bf16x8*>(
                    Vt + (((size_t)(b * 64 + n * 16 + c)) << 11) + key0 + st * 32 + g * 8);
                O[n] = MFMA16(pf, vf, O[n]);
            }
        }
    }

    // ---- epilogue ----
#pragma unroll
    for (int n = 0; n < 4; ++n)
#pragma unroll
        for (int i = 0; i < 4; ++i)
            out[(size_t)(q0g + g * 4 + i) * HD + n * 16 + c] = O[n][i] / l_i[i];
}

// ---------------------------------------------------------------------------
extern "C" void kernel_launch(void* const* d_in, const int* in_sizes, int n_in,
                              void* d_out, int out_size, void* d_ws, size_t ws_size,
                              hipStream_t stream)
{
    (void)in_sizes; (void)n_in; (void)out_size; (void)ws_size;
    const float* x  = (const float*)d_in[0];
    const float* Wq = (const float*)d_in[1];
    const float* bq = (const float*)d_in[2];
    const float* Wk = (const float*)d_in[3];
    const float* bk = (const float*)d_in[4];
    const float* Wv = (const float*)d_in[5];
    const float* bv = (const float*)d_in[6];
    float* out = (float*)d_out;

    char* ws = (char*)d_ws;
    short* Qs    = (short*)(ws);                    // [8192][64] bf16 (q/8)
    short* Kb    = (short*)(ws + (1u << 20));       // [8192][64] bf16
    short* Vb    = (short*)(ws + (2u << 20));       // [8192][64] bf16
    short* Vt    = (short*)(ws + (3u << 20));       // [4][64][2048] bf16
    short* wfrag = (short*)(ws + (4u << 20));       // [3][32][4][64][8] bf16

    wprep_kernel<<<96, 256, 0, stream>>>(Wq, Wk, Wv, wfrag);
    proj_kernel<<<512, 64, 0, stream>>>(x, wfrag, bq, bk, bv, Qs, Kb, Vb);
    vtrans_kernel<<<128, 256, 0, stream>>>(Vb, Vt);
    attn_mfma_kernel<<<512, 64, 0, stream>>>(Qs, Kb, Vt, out);
}

// Round 3
// 87.517 us; speedup vs baseline: 5.4279x; 1.3633x over previous
//
#include <hip/hip_runtime.h>

#define SEQ  2048
#define DIM  1024
#define HD   64
#define NROW 8192
#define CHUNK_TILES 4          // 4 x 64 = 256 keys per partial chunk
#define MAXCH 8                // max chunks per q-tile (32 tiles / 4)

typedef float f32x4  __attribute__((ext_vector_type(4)));
typedef short bf16x8 __attribute__((ext_vector_type(8)));

__device__ __forceinline__ short f2bf(float x) {
    union { float f; unsigned u; } v; v.f = x;
    unsigned r = v.u + 0x7FFFu + ((v.u >> 16) & 1u);
    return (short)(r >> 16);
}

#define MFMA16(a, b, c) __builtin_amdgcn_mfma_f32_16x16x32_bf16((a), (b), (c), 0, 0, 0)

// ---------------------------------------------------------------------------
// wprep: repack Wq/Wk/Wv (fp32 [1024][64]) into bf16 MFMA B-fragment order:
// wfrag[which][kstep 32][nfrag 4][lane 64][8].
// ---------------------------------------------------------------------------
__global__ __launch_bounds__(256) void wprep_kernel(
    const float* __restrict__ Wq, const float* __restrict__ Wk,
    const float* __restrict__ Wv, short* __restrict__ wfrag)
{
    const int idx = blockIdx.x * 256 + threadIdx.x;   // 0..24575
    const int l  = idx & 63;
    const int n  = (idx >> 6) & 3;
    const int ks = (idx >> 8) & 31;
    const int w  = idx >> 13;
    const float* __restrict__ W = (w == 0) ? Wq : (w == 1) ? Wk : Wv;
    bf16x8 v;
#pragma unroll
    for (int j = 0; j < 8; ++j)
        v[j] = f2bf(W[(size_t)(ks * 32 + (l >> 4) * 8 + j) * HD + n * 16 + (l & 15)]);
    *reinterpret_cast<bf16x8*>(wfrag + (size_t)idx * 8) = v;
}

// ---------------------------------------------------------------------------
// proj: one of {q,k,v} per blockIdx.y (3x parallelism vs fused).
// 1 wave/block, 16 rows/wave.  Q stored pre-scaled by 0.125.
// ---------------------------------------------------------------------------
__global__ __launch_bounds__(64) void proj_kernel(
    const float* __restrict__ x, const short* __restrict__ wfrag,
    const float* __restrict__ bq, const float* __restrict__ bk,
    const float* __restrict__ bv,
    short* __restrict__ Qs, short* __restrict__ Kb, short* __restrict__ Vb)
{
    const int lane = threadIdx.x;
    const int c = lane & 15;
    const int g = lane >> 4;
    const int r0 = blockIdx.x * 16;
    const int which = blockIdx.y;

    const float* __restrict__ bias = (which == 0) ? bq : (which == 1) ? bk : bv;
    short* __restrict__ out = (which == 0) ? Qs : (which == 1) ? Kb : Vb;
    const short* __restrict__ wf = wfrag + (size_t)which * 32 * 4 * 64 * 8;
    const float scale = (which == 0) ? 0.125f : 1.0f;

    f32x4 acc[4] = {};

    for (int ks = 0; ks < 32; ++ks) {
        const float* xp = x + (size_t)(r0 + c) * DIM + ks * 32 + g * 8;
        float4 a0 = *reinterpret_cast<const float4*>(xp);
        float4 a1 = *reinterpret_cast<const float4*>(xp + 4);
        float av[8] = {a0.x, a0.y, a0.z, a0.w, a1.x, a1.y, a1.z, a1.w};
        bf16x8 af;
#pragma unroll
        for (int j = 0; j < 8; ++j) af[j] = f2bf(av[j]);
#pragma unroll
        for (int n = 0; n < 4; ++n) {
            bf16x8 bfr = *reinterpret_cast<const bf16x8*>(
                wf + ((size_t)(ks * 4 + n) * 64 + lane) * 8);
            acc[n] = MFMA16(af, bfr, acc[n]);
        }
    }

#pragma unroll
    for (int n = 0; n < 4; ++n) {
        const float bb = bias[n * 16 + c];
#pragma unroll
        for (int i = 0; i < 4; ++i) {
            const size_t row = r0 + g * 4 + i;
            out[row * HD + n * 16 + c] = f2bf((acc[n][i] + bb) * scale);
        }
    }
}

// ---------------------------------------------------------------------------
// vtrans: Vb [8192][64] bf16 -> Vt [4][64][2048] bf16 via LDS transpose.
// ---------------------------------------------------------------------------
__global__ __launch_bounds__(256) void vtrans_kernel(
    const short* __restrict__ Vb, short* __restrict__ Vt)
{
    __shared__ short ts[64][72];
    const int tid = threadIdx.x;
    const int s0g = blockIdx.x * 64;
    const int b   = s0g >> 11;
    const int sb  = s0g & (SEQ - 1);

    {
        const int r = tid >> 2, ch = tid & 3;
        bf16x8 v0 = *reinterpret_cast<const bf16x8*>(Vb + (size_t)(s0g + r) * HD + ch * 16);
        bf16x8 v1 = *reinterpret_cast<const bf16x8*>(Vb + (size_t)(s0g + r) * HD + ch * 16 + 8);
        *reinterpret_cast<bf16x8*>(&ts[r][ch * 16]) = v0;
        *reinterpret_cast<bf16x8*>(&ts[r][ch * 16 + 8]) = v1;
    }
    __syncthreads();
    {
        const int d = tid >> 2, ch = tid & 3;
        bf16x8 o0, o1;
#pragma unroll
        for (int e = 0; e < 8; ++e) o0[e] = ts[ch * 16 + e][d];
#pragma unroll
        for (int e = 0; e < 8; ++e) o1[e] = ts[ch * 16 + 8 + e][d];
        short* dst = Vt + (((size_t)(b * 64 + d)) << 11) + sb + ch * 16;
        *reinterpret_cast<bf16x8*>(dst) = o0;
        *reinterpret_cast<bf16x8*>(dst + 8) = o1;
    }
}

// ===========================================================================
// Split-key flash attention: partial kernel.
// grid = (512 q-tiles, 8 chunks), block = 64 (1 wave).
// Chunk cid covers key tiles [cid*4, min(cid*4+3, tlast)] (256 keys).
// Writes unnormalized O (f32 16x64) + per-row (m,l) to workspace.
// ===========================================================================
__global__ __launch_bounds__(64) void attn_part_kernel(
    const short* __restrict__ Qs, const short* __restrict__ Kb,
    const short* __restrict__ Vt, float* __restrict__ Opart,
    float2* __restrict__ mlpart)
{
    const int qb    = blockIdx.x;          // 0..511
    const int cid   = blockIdx.y;          // 0..7
    const int q0g   = qb * 16;
    const int b     = q0g >> 11;
    const int qbase = q0g & (SEQ - 1);
    const int tlast = qbase >> 6;
    const int t0    = cid * CHUNK_TILES;
    if (t0 > tlast) return;
    const int t1 = min(t0 + CHUNK_TILES - 1, tlast);

    __shared__ short P_lds[16][72];

    const int lane = threadIdx.x;
    const int c = lane & 15;
    const int g = lane >> 4;

    bf16x8 qf[2];
    qf[0] = *reinterpret_cast<const bf16x8*>(Qs + (size_t)(q0g + c) * HD + g * 8);
    qf[1] = *reinterpret_cast<const bf16x8*>(Qs + (size_t)(q0g + c) * HD + 32 + g * 8);

    f32x4 O[4] = {};
    float m_i[4], l_i[4];
#pragma unroll
    for (int i = 0; i < 4; ++i) { m_i[i] = -__builtin_inff(); l_i[i] = 0.f; }

    const size_t krow0 = (size_t)b * SEQ;

    for (int t = t0; t <= t1; ++t) {
        const int key0 = t * 64;

        bf16x8 kf[4][2];
#pragma unroll
        for (int n = 0; n < 4; ++n)
#pragma unroll
            for (int st = 0; st < 2; ++st)
                kf[n][st] = *reinterpret_cast<const bf16x8*>(
                    Kb + (krow0 + key0 + n * 16 + c) * HD + st * 32 + g * 8);

        f32x4 S[4] = {};
#pragma unroll
        for (int st = 0; st < 2; ++st)
#pragma unroll
            for (int n = 0; n < 4; ++n)
                S[n] = MFMA16(qf[st], kf[n][st], S[n]);

        if (t == tlast) {
#pragma unroll
            for (int n = 0; n < 4; ++n)
#pragma unroll
                for (int i = 0; i < 4; ++i)
                    if (key0 + n * 16 + c > qbase + g * 4 + i)
                        S[n][i] = -__builtin_inff();
        }

        float mx[4], corr[4], rs[4];
#pragma unroll
        for (int i = 0; i < 4; ++i)
            mx[i] = fmaxf(fmaxf(S[0][i], S[1][i]), fmaxf(S[2][i], S[3][i]));
#pragma unroll
        for (int off = 1; off <= 8; off <<= 1)
#pragma unroll
            for (int i = 0; i < 4; ++i)
                mx[i] = fmaxf(mx[i], __shfl_xor(mx[i], off, 64));
#pragma unroll
        for (int i = 0; i < 4; ++i) {
            const float mn = fmaxf(m_i[i], mx[i]);
            corr[i] = __expf(m_i[i] - mn);
            m_i[i] = mn;
            rs[i] = 0.f;
        }
#pragma unroll
        for (int n = 0; n < 4; ++n)
#pragma unroll
            for (int i = 0; i < 4; ++i) {
                const float p = __expf(S[n][i] - m_i[i]);
                S[n][i] = p;
                rs[i] += p;
            }
#pragma unroll
        for (int off = 1; off <= 8; off <<= 1)
#pragma unroll
            for (int i = 0; i < 4; ++i)
                rs[i] += __shfl_xor(rs[i], off, 64);
#pragma unroll
        for (int i = 0; i < 4; ++i) l_i[i] = l_i[i] * corr[i] + rs[i];
#pragma unroll
        for (int n = 0; n < 4; ++n)
#pragma unroll
            for (int i = 0; i < 4; ++i) O[n][i] *= corr[i];

#pragma unroll
        for (int n = 0; n < 4; ++n)
#pragma unroll
            for (int i = 0; i < 4; ++i)
                P_lds[g * 4 + i][n * 16 + c] = f2bf(S[n][i]);

#pragma unroll
        for (int st = 0; st < 2; ++st) {
            bf16x8 pf = *reinterpret_cast<const bf16x8*>(&P_lds[c][st * 32 + g * 8]);
#pragma unroll
            for (int n = 0; n < 4; ++n) {
                bf16x8 vf = *reinterpret_cast<const bf16x8*>(
                    Vt + (((size_t)(b * 64 + n * 16 + c)) << 11) + key0 + st * 32 + g * 8);
                O[n] = MFMA16(pf, vf, O[n]);
            }
        }
    }

    // write partials: Opart[(qb*8+cid)][row 16][col 64], ml per row
    float* op = Opart + ((size_t)(qb * MAXCH + cid) * 16) * 64;
#pragma unroll
    for (int n = 0; n < 4; ++n)
#pragma unroll
        for (int i = 0; i < 4; ++i)
            op[(size_t)(g * 4 + i) * 64 + n * 16 + c] = O[n][i];
    if (c == 0) {
#pragma unroll
        for (int i = 0; i < 4; ++i)
            mlpart[(size_t)(qb * MAXCH + cid) * 16 + g * 4 + i] =
                make_float2(m_i[i], l_i[i]);
    }
}

// ---------------------------------------------------------------------------
// combine: grid = 512, block = 256 (4 waves; wave w handles rows w*4..w*4+3).
// ---------------------------------------------------------------------------
__global__ __launch_bounds__(256) void attn_combine_kernel(
    const float* __restrict__ Opart, const float2* __restrict__ mlpart,
    float* __restrict__ out)
{
    const int qb = blockIdx.x;
    const int d  = threadIdx.x & 63;
    const int w  = threadIdx.x >> 6;
    const int qbase = (qb * 16) & (SEQ - 1);
    const int NC = (qbase >> 6) / CHUNK_TILES + 1;

#pragma unroll
    for (int ri = 0; ri < 4; ++ri) {
        const int r = w * 4 + ri;
        float m = -__builtin_inff();
        for (int ci = 0; ci < NC; ++ci)
            m = fmaxf(m, mlpart[(size_t)(qb * MAXCH + ci) * 16 + r].x);
        float l = 0.f, o = 0.f;
        for (int ci = 0; ci < NC; ++ci) {
            const float2 ml = mlpart[(size_t)(qb * MAXCH + ci) * 16 + r];
            const float wgt = __expf(ml.x - m);
            l += wgt * ml.y;
            o += wgt * Opart[((size_t)(qb * MAXCH + ci) * 16 + r) * 64 + d];
        }
        out[(size_t)(qb * 16 + r) * HD + d] = o / l;
    }
}

// ===========================================================================
// Fallback single-pass attention (used only if ws_size is too small for the
// split-K partials).  Identical to the R2 kernel.
// ===========================================================================
__global__ __launch_bounds__(64) void attn_mfma_kernel(
    const short* __restrict__ Qs, const short* __restrict__ Kb,
    const short* __restrict__ Vt, float* __restrict__ out)
{
    __shared__ short P_lds[16][72];
    const int lane = threadIdx.x;
    const int c = lane & 15;
    const int g = lane >> 4;
    const int q0g   = blockIdx.x * 16;
    const int b     = q0g >> 11;
    const int qbase = q0g & (SEQ - 1);

    bf16x8 qf[2];
    qf[0] = *reinterpret_cast<const bf16x8*>(Qs + (size_t)(q0g + c) * HD + g * 8);
    qf[1] = *reinterpret_cast<const bf16x8*>(Qs + (size_t)(q0g + c) * HD + 32 + g * 8);

    f32x4 O[4] = {};
    float m_i[4], l_i[4];
#pragma unroll
    for (int i = 0; i < 4; ++i) { m_i[i] = -__builtin_inff(); l_i[i] = 0.f; }
    const int tlast = qbase >> 6;
    const size_t krow0 = (size_t)b * SEQ;

    for (int t = 0; t <= tlast; ++t) {
        const int key0 = t * 64;
        bf16x8 kf[4][2];
#pragma unroll
        for (int n = 0; n < 4; ++n)
#pragma unroll
            for (int st = 0; st < 2; ++st)
                kf[n][st] = *reinterpret_cast<const bf16x8*>(
                    Kb + (krow0 + key0 + n * 16 + c) * HD + st * 32 + g * 8);
        f32x4 S[4] = {};
#pragma unroll
        for (int st = 0; st < 2; ++st)
#pragma unroll
            for (int n = 0; n < 4; ++n)
                S[n] = MFMA16(qf[st], kf[n][st], S[n]);
        if (t == tlast) {
#pragma unroll
            for (int n = 0; n < 4; ++n)
#pragma unroll
                for (int i = 0; i < 4; ++i)
                    if (key0 + n * 16 + c > qbase + g * 4 + i)
                        S[n][i] = -__builtin_inff();
        }
        float mx[4], corr[4], rs[4];
#pragma unroll
        for (int i = 0; i < 4; ++i)
            mx[i] = fmaxf(fmaxf(S[0][i], S[1][i]), fmaxf(S[2][i], S[3][i]));
#pragma unroll
        for (int off = 1; off <= 8; off <<= 1)
#pragma unroll
            for (int i = 0; i < 4; ++i)
                mx[i] = fmaxf(mx[i], __shfl_xor(mx[i], off, 64));
#pragma unroll
        for (int i = 0; i < 4; ++i) {
            const float mn = fmaxf(m_i[i], mx[i]);
            corr[i] = __expf(m_i[i] - mn);
            m_i[i] = mn;
            rs[i] = 0.f;
        }
#pragma unroll
        for (int n = 0; n < 4; ++n)
#pragma unroll
            for (int i = 0; i < 4; ++i) {
                const float p = __expf(S[n][i] - m_i[i]);
                S[n][i] = p;
                rs[i] += p;
            }
#pragma unroll
        for (int off = 1; off <= 8; off <<= 1)
#pragma unroll
            for (int i = 0; i < 4; ++i)
                rs[i] += __shfl_xor(rs[i], off, 64);
#pragma unroll
        for (int i = 0; i < 4; ++i) l_i[i] = l_i[i] * corr[i] + rs[i];
#pragma unroll
        for (int n = 0; n < 4; ++n)
#pragma unroll
            for (int i = 0; i < 4; ++i) O[n][i] *= corr[i];
#pragma unroll
        for (int n = 0; n < 4; ++n)
#pragma unroll
            for (int i = 0; i < 4; ++i)
                P_lds[g * 4 + i][n * 16 + c] = f2bf(S[n][i]);
#pragma unroll
        for (int st = 0; st < 2; ++st) {
            bf16x8 pf = *reinterpret_cast<const bf16x8*>(&P_lds[c][st * 32 + g * 8]);
#pragma unroll
            for (int n = 0; n < 4; ++n) {
                bf16x8 vf = *reinterpret_cast<const bf16x8*>(
                    Vt + (((size_t)(b * 64 + n * 16 + c)) << 11) + key0 + st * 32 + g * 8);
                O[n] = MFMA16(pf, vf, O[n]);
            }
        }
    }
#pragma unroll
    for (int n = 0; n < 4; ++n)
#pragma unroll
        for (int i = 0; i < 4; ++i)
            out[(size_t)(q0g + g * 4 + i) * HD + n * 16 + c] = O[n][i] / l_i[i];
}

// ---------------------------------------------------------------------------
extern "C" void kernel_launch(void* const* d_in, const int* in_sizes, int n_in,
                              void* d_out, int out_size, void* d_ws, size_t ws_size,
                              hipStream_t stream)
{
    (void)in_sizes; (void)n_in; (void)out_size;
    const float* x  = (const float*)d_in[0];
    const float* Wq = (const float*)d_in[1];
    const float* bq = (const float*)d_in[2];
    const float* Wk = (const float*)d_in[3];
    const float* bk = (const float*)d_in[4];
    const float* Wv = (const float*)d_in[5];
    const float* bv = (const float*)d_in[6];
    float* out = (float*)d_out;

    char* ws = (char*)d_ws;
    short* Qs    = (short*)(ws);                 // 1 MB  [8192][64] bf16 (q/8)
    short* Kb    = (short*)(ws + (1u << 20));    // 1 MB
    short* Vb    = (short*)(ws + (2u << 20));    // 1 MB
    short* Vt    = (short*)(ws + (3u << 20));    // 1 MB  [4][64][2048]
    short* wfrag = (short*)(ws + (4u << 20));    // 384 KB
    float*  Opart  = (float*)(ws + (5u << 20));            // 16 MB
    float2* mlpart = (float2*)(ws + (21u << 20));          // 512 KB
    const size_t needed = (21u << 20) + (1u << 19);

    wprep_kernel<<<96, 256, 0, stream>>>(Wq, Wk, Wv, wfrag);
    proj_kernel<<<dim3(512, 3), 64, 0, stream>>>(x, wfrag, bq, bk, bv, Qs, Kb, Vb);
    vtrans_kernel<<<128, 256, 0, stream>>>(Vb, Vt);

    if (ws_size >= needed) {
        attn_part_kernel<<<dim3(512, MAXCH), 64, 0, stream>>>(Qs, Kb, Vt, Opart, mlpart);
        attn_combine_kernel<<<512, 256, 0, stream>>>(Opart, mlpart, out);
    } else {
        attn_mfma_kernel<<<512, 64, 0, stream>>>(Qs, Kb, Vt, out);
    }
}

// Round 4
// 78.234 us; speedup vs baseline: 6.0719x; 1.1187x over previous
//
#include <hip/hip_runtime.h>

#define SEQ  2048
#define DIM  1024
#define HD   64
#define CHUNK_TILES 4          // 4 x 64 = 256 keys per partial chunk
#define MAXCH 8                // max chunks per q-tile (32 tiles / 4)

typedef float f32x4  __attribute__((ext_vector_type(4)));
typedef short bf16x8 __attribute__((ext_vector_type(8)));

__device__ __forceinline__ short f2bf(float x) {          // RNE (exact)
    union { float f; unsigned u; } v; v.f = x;
    unsigned r = v.u + 0x7FFFu + ((v.u >> 16) & 1u);
    return (short)(r >> 16);
}
__device__ __forceinline__ short f2bf_fast(float x) {     // round-half-up, 2 ops
    union { float f; unsigned u; } v; v.f = x;
    return (short)((v.u + 0x8000u) >> 16);
}

#define MFMA16(a, b, c) __builtin_amdgcn_mfma_f32_16x16x32_bf16((a), (b), (c), 0, 0, 0)

// ---------------------------------------------------------------------------
// wprep: repack Wq/Wk/Wv (fp32 [1024][64]) into bf16 MFMA B-fragment order:
// wfrag[which][kstep 32][nfrag 4][lane 64][8].
// ---------------------------------------------------------------------------
__global__ __launch_bounds__(256) void wprep_kernel(
    const float* __restrict__ Wq, const float* __restrict__ Wk,
    const float* __restrict__ Wv, short* __restrict__ wfrag)
{
    const int idx = blockIdx.x * 256 + threadIdx.x;   // 0..24575
    const int l  = idx & 63;
    const int n  = (idx >> 6) & 3;
    const int ks = (idx >> 8) & 31;
    const int w  = idx >> 13;
    const float* __restrict__ W = (w == 0) ? Wq : (w == 1) ? Wk : Wv;
    bf16x8 v;
#pragma unroll
    for (int j = 0; j < 8; ++j)
        v[j] = f2bf(W[(size_t)(ks * 32 + (l >> 4) * 8 + j) * HD + n * 16 + (l & 15)]);
    *reinterpret_cast<bf16x8*>(wfrag + (size_t)idx * 8) = v;
}

// ---------------------------------------------------------------------------
// proj: one of {q,k,v} per blockIdx.y.  1 wave/block, 16 rows/wave.
// Q pre-scaled by 0.125.  V written TRANSPOSED to Vt via per-wave LDS bounce
// (single wave -> no barrier; compiler orders same-array LDS RAW).
// ---------------------------------------------------------------------------
__global__ __launch_bounds__(64) void proj_kernel(
    const float* __restrict__ x, const short* __restrict__ wfrag,
    const float* __restrict__ bq, const float* __restrict__ bk,
    const float* __restrict__ bv,
    short* __restrict__ Qs, short* __restrict__ Kb, short* __restrict__ Vt)
{
    __shared__ short ts[16][72];

    const int lane = threadIdx.x;
    const int c = lane & 15;
    const int g = lane >> 4;
    const int r0 = blockIdx.x * 16;
    const int which = blockIdx.y;

    const float* __restrict__ bias = (which == 0) ? bq : (which == 1) ? bk : bv;
    const short* __restrict__ wf = wfrag + (size_t)which * 32 * 4 * 64 * 8;

    f32x4 acc[4] = {};

    for (int ks = 0; ks < 32; ++ks) {
        const float* xp = x + (size_t)(r0 + c) * DIM + ks * 32 + g * 8;
        float4 a0 = *reinterpret_cast<const float4*>(xp);
        float4 a1 = *reinterpret_cast<const float4*>(xp + 4);
        float av[8] = {a0.x, a0.y, a0.z, a0.w, a1.x, a1.y, a1.z, a1.w};
        bf16x8 af;
#pragma unroll
        for (int j = 0; j < 8; ++j) af[j] = f2bf_fast(av[j]);
#pragma unroll
        for (int n = 0; n < 4; ++n) {
            bf16x8 bfr = *reinterpret_cast<const bf16x8*>(
                wf + ((size_t)(ks * 4 + n) * 64 + lane) * 8);
            acc[n] = MFMA16(af, bfr, acc[n]);
        }
    }

    if (which < 2) {
        short* __restrict__ out = (which == 0) ? Qs : Kb;
        const float scale = (which == 0) ? 0.125f : 1.0f;
#pragma unroll
        for (int n = 0; n < 4; ++n) {
            const float bb = bias[n * 16 + c];
#pragma unroll
            for (int i = 0; i < 4; ++i)
                out[(size_t)(r0 + g * 4 + i) * HD + n * 16 + c] =
                    f2bf((acc[n][i] + bb) * scale);
        }
    } else {
        // V: bounce through LDS, write transposed Vt[b*64+d][s]
#pragma unroll
        for (int n = 0; n < 4; ++n) {
            const float bb = bias[n * 16 + c];
#pragma unroll
            for (int i = 0; i < 4; ++i)
                ts[g * 4 + i][n * 16 + c] = f2bf(acc[n][i] + bb);
        }
        const int b  = r0 >> 11;
        const int sb = r0 & (SEQ - 1);
        bf16x8 o0, o1;
#pragma unroll
        for (int e = 0; e < 8; ++e) o0[e] = ts[e][lane];
#pragma unroll
        for (int e = 0; e < 8; ++e) o1[e] = ts[8 + e][lane];
        short* dst = Vt + (((size_t)(b * 64 + lane)) << 11) + sb;
        *reinterpret_cast<bf16x8*>(dst)     = o0;
        *reinterpret_cast<bf16x8*>(dst + 8) = o1;
    }
}

// ===========================================================================
// Split-key flash attention, CHUNK-BATCHED softmax.
// grid = (512 q-tiles, 8 chunks), block = 64 (1 wave).
// Phase 1: all QK MFMAs for the <=4 key tiles (long dependence-free run).
// Phase 2: ONE exact softmax over the 16x256 block (no online corrections).
// Phase 3: P -> LDS, then all PV MFMAs.
// Writes unnormalized O (f32 16x64) + per-row (m,l) to workspace.
// ===========================================================================
__global__ __launch_bounds__(64) void attn_part_kernel(
    const short* __restrict__ Qs, const short* __restrict__ Kb,
    const short* __restrict__ Vt, float* __restrict__ Opart,
    float2* __restrict__ mlpart)
{
    const int qb    = blockIdx.x;          // 0..511
    const int cid   = blockIdx.y;          // 0..7
    const int q0g   = qb * 16;
    const int b     = q0g >> 11;
    const int qbase = q0g & (SEQ - 1);
    const int tlast = qbase >> 6;
    const int t0    = cid * CHUNK_TILES;
    if (t0 > tlast) return;
    const int nact = min(CHUNK_TILES, tlast - t0 + 1);   // 1..4 active tiles

    __shared__ short P_lds[16][264];

    const int lane = threadIdx.x;
    const int c = lane & 15;
    const int g = lane >> 4;

    bf16x8 qf[2];
    qf[0] = *reinterpret_cast<const bf16x8*>(Qs + (size_t)(q0g + c) * HD + g * 8);
    qf[1] = *reinterpret_cast<const bf16x8*>(Qs + (size_t)(q0g + c) * HD + 32 + g * 8);

    const size_t krow0 = (size_t)b * SEQ;

    // ---- Phase 1: QK^T for all active tiles ----
    f32x4 S[CHUNK_TILES][4] = {};
#pragma unroll
    for (int tt = 0; tt < CHUNK_TILES; ++tt) {
        if (tt >= nact) continue;          // wave-uniform branch
        const int key0 = (t0 + tt) * 64;
        bf16x8 kf[4][2];
#pragma unroll
        for (int n = 0; n < 4; ++n)
#pragma unroll
            for (int st = 0; st < 2; ++st)
                kf[n][st] = *reinterpret_cast<const bf16x8*>(
                    Kb + (krow0 + key0 + n * 16 + c) * HD + st * 32 + g * 8);
#pragma unroll
        for (int st = 0; st < 2; ++st)
#pragma unroll
            for (int n = 0; n < 4; ++n)
                S[tt][n] = MFMA16(qf[st], kf[n][st], S[tt][n]);
    }

    // causal mask: only the diagonal tile (t == tlast) needs it
    if (tlast - t0 < CHUNK_TILES) {
        const int ttd  = tlast - t0;
        const int key0 = tlast * 64;
#pragma unroll
        for (int tt = 0; tt < CHUNK_TILES; ++tt) {
            if (tt != ttd) continue;
#pragma unroll
            for (int n = 0; n < 4; ++n)
#pragma unroll
                for (int i = 0; i < 4; ++i)
                    if (key0 + n * 16 + c > qbase + g * 4 + i)
                        S[tt][n][i] = -__builtin_inff();
        }
    }

    // ---- Phase 2: one exact softmax over the whole chunk ----
    float mx[4], rs[4];
#pragma unroll
    for (int i = 0; i < 4; ++i) { mx[i] = -__builtin_inff(); rs[i] = 0.f; }
#pragma unroll
    for (int tt = 0; tt < CHUNK_TILES; ++tt) {
        if (tt >= nact) continue;
#pragma unroll
        for (int n = 0; n < 4; ++n)
#pragma unroll
            for (int i = 0; i < 4; ++i)
                mx[i] = fmaxf(mx[i], S[tt][n][i]);
    }
#pragma unroll
    for (int off = 1; off <= 8; off <<= 1)
#pragma unroll
        for (int i = 0; i < 4; ++i)
            mx[i] = fmaxf(mx[i], __shfl_xor(mx[i], off, 64));
#pragma unroll
    for (int tt = 0; tt < CHUNK_TILES; ++tt) {
        if (tt >= nact) continue;
#pragma unroll
        for (int n = 0; n < 4; ++n)
#pragma unroll
            for (int i = 0; i < 4; ++i) {
                const float p = __expf(S[tt][n][i] - mx[i]);
                S[tt][n][i] = p;
                rs[i] += p;
            }
    }
#pragma unroll
    for (int off = 1; off <= 8; off <<= 1)
#pragma unroll
        for (int i = 0; i < 4; ++i)
            rs[i] += __shfl_xor(rs[i], off, 64);

    // ---- Phase 3: P -> LDS, then PV ----
#pragma unroll
    for (int tt = 0; tt < CHUNK_TILES; ++tt) {
        if (tt >= nact) continue;
#pragma unroll
        for (int n = 0; n < 4; ++n)
#pragma unroll
            for (int i = 0; i < 4; ++i)
                P_lds[g * 4 + i][tt * 64 + n * 16 + c] = f2bf_fast(S[tt][n][i]);
    }
    // same-wave LDS RAW: compiler inserts lgkmcnt wait (validated pattern)

    f32x4 O[4] = {};
#pragma unroll
    for (int tt = 0; tt < CHUNK_TILES; ++tt) {
        if (tt >= nact) continue;
        const int key0 = (t0 + tt) * 64;
#pragma unroll
        for (int st = 0; st < 2; ++st) {
            bf16x8 pf = *reinterpret_cast<const bf16x8*>(
                &P_lds[c][tt * 64 + st * 32 + g * 8]);
#pragma unroll
            for (int n = 0; n < 4; ++n) {
                bf16x8 vf = *reinterpret_cast<const bf16x8*>(
                    Vt + (((size_t)(b * 64 + n * 16 + c)) << 11) + key0 + st * 32 + g * 8);
                O[n] = MFMA16(pf, vf, O[n]);
            }
        }
    }

    // ---- write partials ----
    float* op = Opart + ((size_t)(qb * MAXCH + cid) * 16) * 64;
#pragma unroll
    for (int n = 0; n < 4; ++n)
#pragma unroll
        for (int i = 0; i < 4; ++i)
            op[(size_t)(g * 4 + i) * 64 + n * 16 + c] = O[n][i];
    if (c == 0) {
#pragma unroll
        for (int i = 0; i < 4; ++i)
            mlpart[(size_t)(qb * MAXCH + cid) * 16 + g * 4 + i] =
                make_float2(mx[i], rs[i]);
    }
}

// ---------------------------------------------------------------------------
// combine: grid = 512, block = 256 (4 waves; wave w handles rows w*4..w*4+3).
// ---------------------------------------------------------------------------
__global__ __launch_bounds__(256) void attn_combine_kernel(
    const float* __restrict__ Opart, const float2* __restrict__ mlpart,
    float* __restrict__ out)
{
    const int qb = blockIdx.x;
    const int d  = threadIdx.x & 63;
    const int w  = threadIdx.x >> 6;
    const int qbase = (qb * 16) & (SEQ - 1);
    const int NC = (qbase >> 6) / CHUNK_TILES + 1;

#pragma unroll
    for (int ri = 0; ri < 4; ++ri) {
        const int r = w * 4 + ri;
        float m = -__builtin_inff();
        for (int ci = 0; ci < NC; ++ci)
            m = fmaxf(m, mlpart[(size_t)(qb * MAXCH + ci) * 16 + r].x);
        float l = 0.f, o = 0.f;
        for (int ci = 0; ci < NC; ++ci) {
            const float2 ml = mlpart[(size_t)(qb * MAXCH + ci) * 16 + r];
            const float wgt = __expf(ml.x - m);
            l += wgt * ml.y;
            o += wgt * Opart[((size_t)(qb * MAXCH + ci) * 16 + r) * 64 + d];
        }
        out[(size_t)(qb * 16 + r) * HD + d] = o / l;
    }
}

// ===========================================================================
// Fallback single-pass attention (only if ws_size too small for split-K).
// ===========================================================================
__global__ __launch_bounds__(64) void attn_mfma_kernel(
    const short* __restrict__ Qs, const short* __restrict__ Kb,
    const short* __restrict__ Vt, float* __restrict__ out)
{
    __shared__ short P_lds[16][72];
    const int lane = threadIdx.x;
    const int c = lane & 15;
    const int g = lane >> 4;
    const int q0g   = blockIdx.x * 16;
    const int b     = q0g >> 11;
    const int qbase = q0g & (SEQ - 1);

    bf16x8 qf[2];
    qf[0] = *reinterpret_cast<const bf16x8*>(Qs + (size_t)(q0g + c) * HD + g * 8);
    qf[1] = *reinterpret_cast<const bf16x8*>(Qs + (size_t)(q0g + c) * HD + 32 + g * 8);

    f32x4 O[4] = {};
    float m_i[4], l_i[4];
#pragma unroll
    for (int i = 0; i < 4; ++i) { m_i[i] = -__builtin_inff(); l_i[i] = 0.f; }
    const int tlast = qbase >> 6;
    const size_t krow0 = (size_t)b * SEQ;

    for (int t = 0; t <= tlast; ++t) {
        const int key0 = t * 64;
        bf16x8 kf[4][2];
#pragma unroll
        for (int n = 0; n < 4; ++n)
#pragma unroll
            for (int st = 0; st < 2; ++st)
                kf[n][st] = *reinterpret_cast<const bf16x8*>(
                    Kb + (krow0 + key0 + n * 16 + c) * HD + st * 32 + g * 8);
        f32x4 S[4] = {};
#pragma unroll
        for (int st = 0; st < 2; ++st)
#pragma unroll
            for (int n = 0; n < 4; ++n)
                S[n] = MFMA16(qf[st], kf[n][st], S[n]);
        if (t == tlast) {
#pragma unroll
            for (int n = 0; n < 4; ++n)
#pragma unroll
                for (int i = 0; i < 4; ++i)
                    if (key0 + n * 16 + c > qbase + g * 4 + i)
                        S[n][i] = -__builtin_inff();
        }
        float mx[4], corr[4], rs[4];
#pragma unroll
        for (int i = 0; i < 4; ++i)
            mx[i] = fmaxf(fmaxf(S[0][i], S[1][i]), fmaxf(S[2][i], S[3][i]));
#pragma unroll
        for (int off = 1; off <= 8; off <<= 1)
#pragma unroll
            for (int i = 0; i < 4; ++i)
                mx[i] = fmaxf(mx[i], __shfl_xor(mx[i], off, 64));
#pragma unroll
        for (int i = 0; i < 4; ++i) {
            const float mn = fmaxf(m_i[i], mx[i]);
            corr[i] = __expf(m_i[i] - mn);
            m_i[i] = mn;
            rs[i] = 0.f;
        }
#pragma unroll
        for (int n = 0; n < 4; ++n)
#pragma unroll
            for (int i = 0; i < 4; ++i) {
                const float p = __expf(S[n][i] - m_i[i]);
                S[n][i] = p;
                rs[i] += p;
            }
#pragma unroll
        for (int off = 1; off <= 8; off <<= 1)
#pragma unroll
            for (int i = 0; i < 4; ++i)
                rs[i] += __shfl_xor(rs[i], off, 64);
#pragma unroll
        for (int i = 0; i < 4; ++i) l_i[i] = l_i[i] * corr[i] + rs[i];
#pragma unroll
        for (int n = 0; n < 4; ++n)
#pragma unroll
            for (int i = 0; i < 4; ++i) O[n][i] *= corr[i];
#pragma unroll
        for (int n = 0; n < 4; ++n)
#pragma unroll
            for (int i = 0; i < 4; ++i)
                P_lds[g * 4 + i][n * 16 + c] = f2bf_fast(S[n][i]);
#pragma unroll
        for (int st = 0; st < 2; ++st) {
            bf16x8 pf = *reinterpret_cast<const bf16x8*>(&P_lds[c][st * 32 + g * 8]);
#pragma unroll
            for (int n = 0; n < 4; ++n) {
                bf16x8 vf = *reinterpret_cast<const bf16x8*>(
                    Vt + (((size_t)(b * 64 + n * 16 + c)) << 11) + key0 + st * 32 + g * 8);
                O[n] = MFMA16(pf, vf, O[n]);
            }
        }
    }
#pragma unroll
    for (int n = 0; n < 4; ++n)
#pragma unroll
        for (int i = 0; i < 4; ++i)
            out[(size_t)(q0g + g * 4 + i) * HD + n * 16 + c] = O[n][i] / l_i[i];
}

// ---------------------------------------------------------------------------
extern "C" void kernel_launch(void* const* d_in, const int* in_sizes, int n_in,
                              void* d_out, int out_size, void* d_ws, size_t ws_size,
                              hipStream_t stream)
{
    (void)in_sizes; (void)n_in; (void)out_size;
    const float* x  = (const float*)d_in[0];
    const float* Wq = (const float*)d_in[1];
    const float* bq = (const float*)d_in[2];
    const float* Wk = (const float*)d_in[3];
    const float* bk = (const float*)d_in[4];
    const float* Wv = (const float*)d_in[5];
    const float* bv = (const float*)d_in[6];
    float* out = (float*)d_out;

    char* ws = (char*)d_ws;
    short* Qs    = (short*)(ws);                 // 1 MB  [8192][64] bf16 (q/8)
    short* Kb    = (short*)(ws + (1u << 20));    // 1 MB
    short* Vt    = (short*)(ws + (2u << 20));    // 1 MB  [4][64][2048]
    short* wfrag = (short*)(ws + (3u << 20));    // 384 KB
    float*  Opart  = (float*)(ws + (4u << 20));            // 16 MB
    float2* mlpart = (float2*)(ws + (20u << 20));          // 512 KB
    const size_t needed = (20u << 20) + (1u << 19);

    wprep_kernel<<<96, 256, 0, stream>>>(Wq, Wk, Wv, wfrag);
    proj_kernel<<<dim3(512, 3), 64, 0, stream>>>(x, wfrag, bq, bk, bv, Qs, Kb, Vt);

    if (ws_size >= needed) {
        attn_part_kernel<<<dim3(512, MAXCH), 64, 0, stream>>>(Qs, Kb, Vt, Opart, mlpart);
        attn_combine_kernel<<<512, 256, 0, stream>>>(Opart, mlpart, out);
    } else {
        attn_mfma_kernel<<<512, 64, 0, stream>>>(Qs, Kb, Vt, out);
    }
}